// Round 1
// baseline (1350.565 us; speedup 1.0000x reference)
//
#include <hip/hip_runtime.h>
#include <math.h>

#define B_   64
#define S_   1024
#define DK_  128
#define DV_  128
#define LR_    0.1f
#define THR_   0.1f
#define ITEMP_ 10.0f   // 1/temperature
#define EPS_   1e-6f

struct StepRegs {
  float k[64];   // this thread's 64-col chunk of k for a step
  float ka, kb;  // lane-indexed elements (for ||k||^2 wave-reduce)
  float v;       // v[row]
};

__global__ __launch_bounds__(256, 1)
void sgm_kernel(const float* __restrict__ mem_in,
                const float* __restrict__ key,
                const float* __restrict__ value,
                float* __restrict__ out) {
  const int b    = blockIdx.x;
  const int tid  = threadIdx.x;
  const int r    = tid >> 1;      // output row 0..127
  const int h    = tid & 1;       // column half
  const int col0 = h * 64;
  const int lane = tid & 63;
  const int wv   = tid >> 6;      // wave id 0..3

  __shared__ float red[2][4];     // parity-alternating cross-wave partials

  // ---- memory state into registers (64 floats/thread) ----
  float m[64];
  {
    const float* mp = mem_in + ((size_t)b * DV_ + r) * DK_ + col0;
    #pragma unroll
    for (int i = 0; i < 16; ++i) {
      float4 t = reinterpret_cast<const float4*>(mp)[i];
      m[4*i+0] = t.x; m[4*i+1] = t.y; m[4*i+2] = t.z; m[4*i+3] = t.w;
    }
  }

  const float* kbase = key   + (size_t)b * S_ * DK_;
  const float* vbase = value + (size_t)b * S_ * DV_;
  float*       gout  = out + (size_t)B_ * DV_ * DK_ + (size_t)b * S_;

  auto load_step = [&](int s, StepRegs& R) {
    const float* kp = kbase + (size_t)s * DK_ + col0;
    #pragma unroll
    for (int i = 0; i < 16; ++i) {
      float4 t = reinterpret_cast<const float4*>(kp)[i];
      R.k[4*i+0] = t.x; R.k[4*i+1] = t.y; R.k[4*i+2] = t.z; R.k[4*i+3] = t.w;
    }
    R.ka = kbase[(size_t)s * DK_ + lane];
    R.kb = kbase[(size_t)s * DK_ + 64 + lane];
    R.v  = vbase[(size_t)s * DV_ + r];
  };

  auto compute = [&](int s, const StepRegs& R) {
    // ||k||^2: wave-redundant (every wave holds all 128 elems across lanes)
    float kk = R.ka * R.ka + R.kb * R.kb;
    #pragma unroll
    for (int mm = 1; mm < 64; mm <<= 1) kk += __shfl_xor(kk, mm, 64);
    const float rinorm = 1.0f / (sqrtf(kk) + EPS_);

    // raw dot: mem[r][:] . k[:]  (this thread's 64-col partial)
    float d0 = 0.f, d1 = 0.f, d2 = 0.f, d3 = 0.f;
    #pragma unroll
    for (int i = 0; i < 64; i += 4) {
      d0 = fmaf(m[i+0], R.k[i+0], d0);
      d1 = fmaf(m[i+1], R.k[i+1], d1);
      d2 = fmaf(m[i+2], R.k[i+2], d2);
      d3 = fmaf(m[i+3], R.k[i+3], d3);
    }
    float dpart = (d0 + d1) + (d2 + d3);
    const float d         = dpart + __shfl_xor(dpart, 1, 64); // pair-combine halves
    const float predicted = d * rinorm;
    const float surprise  = predicted - R.v;
    const float sq        = surprise * surprise;

    // s_norm^2: wave-reduce (values pair-duplicated -> 2x), then LDS combine
    float ws = sq;
    #pragma unroll
    for (int mm = 1; mm < 64; mm <<= 1) ws += __shfl_xor(ws, mm, 64);
    if (lane == 0) red[s & 1][wv] = ws;
    __syncthreads();
    const float* rr = red[s & 1];
    const float s2 = 0.5f * ((rr[0] + rr[1]) + (rr[2] + rr[3]));

    const float snorm = sqrtf(s2);
    const float gate  = 1.0f / (1.0f + expf(-(snorm - THR_) * ITEMP_));

    // mem -= gate * (pred + lr*surprise) * k_n  ; fold rinorm into scalar
    const float coef = gate * (predicted + LR_ * surprise) * rinorm;
    #pragma unroll
    for (int i = 0; i < 64; ++i) m[i] = fmaf(-coef, R.k[i], m[i]);

    if (tid == 0) gout[s] = gate;
  };

  StepRegs A, Bv;
  load_step(0, A);
  for (int s = 0; s < S_; s += 2) {
    load_step(s + 1, Bv);          // prefetch while computing A
    compute(s, A);
    const int n2 = (s + 2 < S_) ? (s + 2) : (S_ - 1); // clamp (discarded)
    load_step(n2, A);              // prefetch while computing Bv
    compute(s + 1, Bv);
  }

  // ---- write final memory ----
  float* op = out + ((size_t)b * DV_ + r) * DK_ + col0;
  #pragma unroll
  for (int i = 0; i < 16; ++i) {
    float4 t = make_float4(m[4*i+0], m[4*i+1], m[4*i+2], m[4*i+3]);
    reinterpret_cast<float4*>(op)[i] = t;
  }
}

extern "C" void kernel_launch(void* const* d_in, const int* in_sizes, int n_in,
                              void* d_out, int out_size, void* d_ws, size_t ws_size,
                              hipStream_t stream) {
  const float* mem = (const float*)d_in[0];
  const float* key = (const float*)d_in[1];
  const float* val = (const float*)d_in[2];
  float* out = (float*)d_out;
  sgm_kernel<<<B_, 256, 0, stream>>>(mem, key, val, out);
}